// Round 7
// baseline (1340.960 us; speedup 1.0000x reference)
//
#include <hip/hip_runtime.h>
#include <hip/hip_bf16.h>

// Round 7 (= round 4 kernel, resubmitted; rounds 4-6 were infra timeouts):
// counted-vmcnt pipeline (T3/T4 minimum), unrolled K-loop.
//  - weights pre-packed f16 in d_ws, chunk-coalesced -> linear global_load_lds
//  - A loaded global->reg per wave, cvt f32->f16 at use; no A in LDS
//  - raw s_barrier + s_waitcnt vmcnt(8): weight stages drained, 8 A-loads stay
//    in flight across every barrier. No vmcnt(0) in the main loop.
//  - TILE_N=128, 8 waves (2M x 4N), 32 MFMA/wave/step, 12 steps unrolled.

#define MOLC 128
#define HIDC 256
#define KTOT 384
#define NKT  12
#define TILE_N 128
#define NTH  512

typedef _Float16 f16;
typedef _Float16 f16x8 __attribute__((ext_vector_type(8)));
typedef float    f32x4 __attribute__((ext_vector_type(4)));

#define SBAR()  __builtin_amdgcn_s_barrier()
#define SCHED() __builtin_amdgcn_sched_barrier(0)
#define WAITV8() asm volatile("s_waitcnt vmcnt(8)" ::: "memory")

#define GLL16(g, l) __builtin_amdgcn_global_load_lds(                          \
    (const __attribute__((address_space(1))) uint32_t*)(g),                    \
    (__attribute__((address_space(3))) uint32_t*)(l), 16, 0, 0)

__device__ __forceinline__ f16x8 cvt8(float4 a, float4 b) {
  f16x8 r;
  r[0] = (f16)a.x; r[1] = (f16)a.y; r[2] = (f16)a.z; r[3] = (f16)a.w;
  r[4] = (f16)b.x; r[5] = (f16)b.y; r[6] = (f16)b.z; r[7] = (f16)b.w;
  return r;
}

__global__ void zero_out_kernel(float4* __restrict__ p, int n4) {
  int i = blockIdx.x * blockDim.x + threadIdx.x;
  if (i < n4) p[i] = make_float4(0.f, 0.f, 0.f, 0.f);
}

// Pack weights -> f16, chunk-coalesced. Unit s = one f16x8 (16B).
// W1: s in [0,12288): ks=s>>10, g=(s&1023)>>6, lane=s&63 ; ch=g*16+(lane&15)
// W2: s2=s-12288 in [0,8192): same, base +98304 f16.
__global__ void pack_weights_kernel(const float* __restrict__ W_lin,
                                    const float* __restrict__ W_last,
                                    f16* __restrict__ ws) {
  int s = blockIdx.x * blockDim.x + threadIdx.x;
  if (s >= 20480) return;
  const float* src;
  f16* dst;
  if (s < 12288) {
    int ks = s >> 10, rem = s & 1023, g = rem >> 6, lane = rem & 63;
    int lr = lane & 15, lq = lane >> 4;
    src = W_lin + (size_t)(g * 16 + lr) * KTOT + ks * 32 + lq * 8;
    dst = ws + (size_t)s * 8;
  } else {
    int s2 = s - 12288;
    int ks = s2 >> 10, rem = s2 & 1023, g = rem >> 6, lane = rem & 63;
    int lr = lane & 15, lq = lane >> 4;
    src = W_last + (size_t)(g * 16 + lr) * HIDC + ks * 32 + lq * 8;
    dst = ws + 98304 + (size_t)s2 * 8;
  }
  float4 a = ((const float4*)src)[0];
  float4 b = ((const float4*)src)[1];
  *(f16x8*)dst = cvt8(a, b);
}

__global__ __launch_bounds__(NTH, 2) void attn_pool_kernel(
    const float* __restrict__ input_rep,
    const float* __restrict__ final_rep,
    const int*   __restrict__ gidx,
    const f16*   __restrict__ ws,
    const float* __restrict__ b_lin,
    const float* __restrict__ b_last,
    float* __restrict__ out,
    int n_nodes)
{
  __shared__ f16 W[2][16384];   // [buf][ W1: 0..8191 | W2: 8192..16383 ]  (64KB)
  __shared__ int gi[TILE_N];

  const int t    = threadIdx.x;
  const int lane = t & 63;
  const int wv   = t >> 6;       // 0..7
  const int wm   = wv >> 2;      // node half
  const int wn   = wv & 3;       // channel group (64 ch)
  const int lr   = lane & 15;
  const int lq   = lane >> 4;
  const int nb   = blockIdx.x * TILE_N;
  const int wch  = wn * 64;

  if (t < TILE_N) gi[t] = (nb + t < n_nodes) ? gidx[nb + t] : -1;

  // per-i clamped row offsets (f32 elems); padding rows read node n-1, filtered at scatter
  int offin[4], offfin[4];
#pragma unroll
  for (int i = 0; i < 4; ++i) {
    int r = nb + wm * 64 + i * 16 + lr;
    r = min(r, n_nodes - 1);
    offin[i]  = r * MOLC;
    offfin[i] = r * HIDC;
  }

  auto stageW1 = [&](int ks, int b) {
#pragma unroll
    for (int rd = 0; rd < 2; ++rd)
      GLL16(ws + ks * 8192 + rd * 4096 + t * 8, &W[b][rd * 4096 + t * 8]);
  };
  auto stageW2 = [&](int ks, int b) {
#pragma unroll
    for (int rd = 0; rd < 2; ++rd)
      GLL16(ws + 98304 + (ks - 4) * 8192 + rd * 4096 + t * 8,
            &W[b][8192 + rd * 4096 + t * 8]);
  };

  float4 ra[4][2];
  auto loadA = [&](int ks) {
#pragma unroll
    for (int i = 0; i < 4; ++i) {
      const float* p = (ks < 4)
          ? input_rep + offin[i]  + ks * 32 + lq * 8
          : final_rep + offfin[i] + (ks - 4) * 32 + lq * 8;
      ra[i][0] = ((const float4*)p)[0];
      ra[i][1] = ((const float4*)p)[1];
    }
  };

  f32x4 acc1[4][4], acc2[4][4];
#pragma unroll
  for (int i = 0; i < 4; ++i)
#pragma unroll
    for (int j = 0; j < 4; ++j) { acc1[i][j] = (f32x4)(0.f); acc2[i][j] = (f32x4)(0.f); }

  // ---- prologue: stage W(0), issue A(0) ----
  stageW1(0, 0);
  SCHED();
  loadA(0);
  SCHED();
  asm volatile("s_waitcnt lgkmcnt(0)" ::: "memory");  // gi LDS write drained
  WAITV8();   // outstanding: gi-read + W(0)[2] + A(0)[8] -> retires gi + W(0)
  SCHED();
  SBAR();

  // ---- main loop, fully unrolled; one raw barrier per step, vmcnt(8) only ----
#pragma unroll
  for (int ks = 0; ks < NKT; ++ks) {
    const int b = ks & 1, nx = b ^ 1;

    if (ks + 1 < NKT) {
      stageW1(ks + 1, nx);
      if (ks + 1 >= 4) stageW2(ks + 1, nx);
    }
    SCHED();

    // cvt current A (compiler emits counted vmcnt: only A(ks) must land)
    f16x8 af[4];
#pragma unroll
    for (int i = 0; i < 4; ++i) af[i] = cvt8(ra[i][0], ra[i][1]);
    SCHED();

    if (ks + 1 < NKT) loadA(ks + 1);   // 8 loads; ride across the barrier
    SCHED();

    {
      f16x8 bf[4];
#pragma unroll
      for (int j = 0; j < 4; ++j)
        bf[j] = *(const f16x8*)&W[b][(wn * 4 + j) * 512 + (lq * 16 + lr) * 8];
#pragma unroll
      for (int i = 0; i < 4; ++i)
#pragma unroll
        for (int j = 0; j < 4; ++j)
          acc1[i][j] = __builtin_amdgcn_mfma_f32_16x16x32_f16(af[i], bf[j], acc1[i][j], 0, 0, 0);
    }
    if (ks >= 4) {
      f16x8 bf[4];
#pragma unroll
      for (int j = 0; j < 4; ++j)
        bf[j] = *(const f16x8*)&W[b][8192 + (wn * 4 + j) * 512 + (lq * 16 + lr) * 8];
#pragma unroll
      for (int i = 0; i < 4; ++i)
#pragma unroll
        for (int j = 0; j < 4; ++j)
          acc2[i][j] = __builtin_amdgcn_mfma_f32_16x16x32_f16(af[i], bf[j], acc2[i][j], 0, 0, 0);
    }

    if (ks + 1 < NKT) {
      WAITV8();   // outstanding: W(ks+1)[2-4] + A(ks+1)[8] -> retires W(ks+1)
      SCHED();
      SBAR();
    }
  }

  // ---- epilogue: g = sigmoid(acc1 + b_lin) * (acc2 + b_last) ----
  float bl[4], bb[4];
#pragma unroll
  for (int j = 0; j < 4; ++j) {
    bl[j] = b_lin[wch + j * 16 + lr];
    bb[j] = b_last[wch + j * 16 + lr];
  }
#pragma unroll
  for (int i = 0; i < 4; ++i)
#pragma unroll
    for (int j = 0; j < 4; ++j)
#pragma unroll
      for (int r = 0; r < 4; ++r) {
        float a   = acc1[i][j][r] + bl[j];
        float att = 1.f / (1.f + __expf(-a));
        acc1[i][j][r] = att * (acc2[i][j][r] + bb[j]);
      }

  // ---- scatter: segment scan over sorted gidx, shfl-reduce, atomicAdd ----
  // C/D map: node = nb + wm*64 + i*16 + lq*4 + r ; ch = wch + j*16 + lr
  for (int i = 0; i < 4; ++i) {
    const int base = wm * 64 + i * 16;
    int myg[4];
#pragma unroll
    for (int r = 0; r < 4; ++r) myg[r] = gi[base + lq * 4 + r];

    int s = 0;
    while (s < 16) {
      const int gid = gi[base + s];
      int e = s + 1;
      while (e < 16 && gi[base + e] == gid) ++e;
      if (gid >= 0) {
#pragma unroll
        for (int j = 0; j < 4; ++j) {
          float v = 0.f;
#pragma unroll
          for (int r = 0; r < 4; ++r)
            if (myg[r] == gid) v += acc1[i][j][r];
          v += __shfl_xor(v, 16);
          v += __shfl_xor(v, 32);
          if (lane < 16)
            atomicAdd(&out[(size_t)gid * HIDC + wch + j * 16 + lane], v);
        }
      }
      s = e;
    }
  }
}

extern "C" void kernel_launch(void* const* d_in, const int* in_sizes, int n_in,
                              void* d_out, int out_size, void* d_ws, size_t ws_size,
                              hipStream_t stream) {
  const float* input_rep = (const float*)d_in[0];
  const float* final_rep = (const float*)d_in[1];
  const int*   gidx      = (const int*)d_in[2];
  const float* W_lin     = (const float*)d_in[3];
  const float* b_lin     = (const float*)d_in[4];
  const float* W_last    = (const float*)d_in[5];
  const float* b_last    = (const float*)d_in[6];
  float* out = (float*)d_out;
  f16*   ws  = (f16*)d_ws;

  const int n_nodes = in_sizes[0] / MOLC;

  const int n4 = out_size / 4;
  zero_out_kernel<<<(n4 + 255) / 256, 256, 0, stream>>>((float4*)out, n4);

  pack_weights_kernel<<<80, 256, 0, stream>>>(W_lin, W_last, ws);

  const int grid = (n_nodes + TILE_N - 1) / TILE_N;
  attn_pool_kernel<<<grid, NTH, 0, stream>>>(
      input_rep, final_rep, gidx, ws, b_lin, b_last, out, n_nodes);
}